// Round 1
// baseline (156.986 us; speedup 1.0000x reference)
//
#include <hip/hip_runtime.h>

typedef long long i64;
typedef unsigned long long u64;

// ---------------------------------------------------------------------------
// Established facts (R1-R9):
//  - int64 inputs; int32 output [total*3] neg then [total] keep.
//  - R4/R8: PASS, kernel ~53 us, VALUBusy ~45%, occ ~71%, FETCH 9.5 MB,
//    WRITE 65.5 MB (1.2 TB/s -- far from BW ceiling).
//  - R8 (broadcast tail search): NEUTRAL => NOT gather/L2-BW bound; bound by
//    the dependent-load chain of the search + VALU issue.
//  - Harness dur_us includes a fixed ~43 us fillBufferAligned (268 MB) we
//    cannot remove; only the sampling dispatch is tunable.
//  - Proven shell: ONE dispatch, width probe, no d_ws, no atomics, no
//    cross-lane intrinsics.
// R10: K=4 items/thread, lockstep-interleaved interpolation searches.
//  Four independent probe loads issued back-to-back per iteration (ILP 4 on
//  the latency chain), pos-triple + division amortized 4x, stores vectorized
//  to dwordx4. Probes are branchless (clamped, always in-range) so loads are
//  not serialized behind per-chain exec-mask branches.
// ---------------------------------------------------------------------------

#ifndef K_ITEMS
#define K_ITEMS 4
#endif

// ---------------- scalar fallback (tail only; proven R4 body) ---------------

template <typename T>
__device__ __forceinline__ bool interp_member(const T* __restrict__ table,
                                              int L, u64 key) {
    u64 v0 = (u64)table[0];
    u64 vN = (u64)table[L - 1];
    if (key <= v0) return key == v0;
    if (key >= vN) return key == vN;
    int lo = 0, hi = L - 1;
    u64 vlo = v0, vhi = vN;
    for (int it = 0; it < 12 && hi - lo > 8; ++it) {
        float f = (float)(key - vlo) * __builtin_amdgcn_rcpf((float)(vhi - vlo));
        int mid = lo + (int)(f * (float)(hi - lo));
        if (mid <= lo) mid = lo + 1;
        if (mid >= hi) mid = hi - 1;
        u64 v = (u64)table[mid];
        if (v == key) return true;
        if (v < key) { lo = mid; vlo = v; }
        else         { hi = mid; vhi = v; }
    }
    while (hi - lo > 8) {
        int mid = lo + ((hi - lo) >> 1);
        u64 v = (u64)table[mid];
        if (v == key) return true;
        if (v < key) lo = mid; else hi = mid;
    }
    bool eq = false;
    for (int j = lo + 1; j < hi; ++j) eq |= ((u64)table[j] == key);
    return eq;
}

template <typename T>
__device__ __forceinline__ void sample_body(
    const T* __restrict__ pos, const T* __restrict__ rand_vals,
    const T* __restrict__ table,
    int* __restrict__ out_neg, int* __restrict__ out_keep,
    unsigned i, int split, int L, unsigned num_negs)
{
    unsigned b = i / num_negs;
    i64 h = (i64)pos[3 * b + 0];
    i64 r = (i64)pos[3 * b + 1];
    i64 t = (i64)pos[3 * b + 2];
    i64 rv = (i64)rand_vals[i];

    const bool corrupt_head = (i < (unsigned)split);
    i64 orig = corrupt_head ? h : t;
    i64 repl = rv + (((rv >= orig) & (orig > 0)) ? 1 : 0);
    if (corrupt_head) h = repl; else t = repl;

    u64 key = ((u64)h << 42) | ((u64)r << 21) | (u64)t;
    bool in_set = interp_member(table, L, key);

    out_neg[3 * (size_t)i + 0] = (int)h;
    out_neg[3 * (size_t)i + 1] = (int)r;
    out_neg[3 * (size_t)i + 2] = (int)t;
    out_keep[i] = in_set ? 0 : 1;
}

// ---------------- K-wide lockstep body (main path) --------------------------

template <typename T>
__device__ __forceinline__ void sample_body_k(
    const T* __restrict__ pos, const T* __restrict__ rand_vals,
    const T* __restrict__ table,
    int* __restrict__ out_neg, int* __restrict__ out_keep,
    unsigned i0, int split, int L, unsigned num_negs)
{
    u64 v0 = (u64)table[0];          // wave-uniform -> scalar loads
    u64 vN = (u64)table[L - 1];

    // one division per K items (pow2 fast path: num_negs=64 in practice)
    unsigned b;
    if ((num_negs & (num_negs - 1)) == 0u) b = i0 >> __builtin_ctz(num_negs);
    else                                   b = i0 / num_negs;
    unsigned r_in_b = i0 - b * num_negs;

    i64 ph = (i64)pos[3 * (size_t)b + 0];
    i64 pr = (i64)pos[3 * (size_t)b + 1];
    i64 pt = (i64)pos[3 * (size_t)b + 2];

    u64 key[K_ITEMS];
    int lo[K_ITEMS], hi[K_ITEMS];
    u64 vlo[K_ITEMS], vhi[K_ITEMS];
    bool found[K_ITEMS], act[K_ITEMS];
    int hv[K_ITEMS], rv2[K_ITEMS], tv[K_ITEMS];

    #pragma unroll
    for (int k = 0; k < K_ITEMS; ++k) {
        if (k > 0) {                       // group rollover: never when K|num_negs
            ++r_in_b;
            if (r_in_b == num_negs) {
                r_in_b = 0; ++b;
                ph = (i64)pos[3 * (size_t)b + 0];
                pr = (i64)pos[3 * (size_t)b + 1];
                pt = (i64)pos[3 * (size_t)b + 2];
            }
        }
        unsigned i = i0 + (unsigned)k;
        i64 h = ph, r = pr, t = pt;
        i64 rv = (i64)rand_vals[i];

        const bool corrupt_head = (i < (unsigned)split);
        i64 orig = corrupt_head ? h : t;
        i64 repl = rv + (((rv >= orig) & (orig > 0)) ? 1 : 0);
        if (corrupt_head) h = repl; else t = repl;

        u64 kk = ((u64)h << 42) | ((u64)r << 21) | (u64)t;
        key[k] = kk;
        hv[k] = (int)h; rv2[k] = (int)r; tv[k] = (int)t;

        found[k] = (kk == v0) | (kk == vN);
        act[k]   = (kk > v0) & (kk < vN);
        lo[k] = 0; hi[k] = L - 1; vlo[k] = v0; vhi[k] = vN;
    }

    // neg output: 12 consecutive ints, byte offset 48*tid -> 16B aligned.
    // Store now (fire-and-forget) to free the value registers for the search.
    {
        int4* np4 = (int4*)(out_neg + 3 * (size_t)i0);
        np4[0] = make_int4(hv[0], rv2[0], tv[0], hv[1]);
        np4[1] = make_int4(rv2[1], tv[1], hv[2], rv2[2]);
        np4[2] = make_int4(tv[2], hv[3], rv2[3], tv[3]);
    }

    // lockstep interpolation: all K probe loads issued back-to-back each iter
    #pragma unroll 1
    for (int it = 0; it < 12; ++it) {
        if (!(act[0] | act[1] | act[2] | act[3])) break;
        int mid[K_ITEMS];
        u64 v[K_ITEMS];
        #pragma unroll
        for (int k = 0; k < K_ITEMS; ++k) {
            // branchless, always-in-range probe (inactive chains probe a
            // frozen, still-valid window; result is ignored)
            float num = (float)(key[k] - vlo[k]);
            float den = (float)(vhi[k] - vlo[k]);
            float f = num * __builtin_amdgcn_rcpf(den);
            f = fminf(fmaxf(f, 0.0f), 1.0f);
            int m = lo[k] + (int)(f * (float)(hi[k] - lo[k]));
            if (m <= lo[k]) m = lo[k] + 1;
            if (m >= hi[k]) m = hi[k] - 1;
            mid[k] = m;
            v[k] = (u64)table[m];          // K independent loads, one vmcnt wait
        }
        #pragma unroll
        for (int k = 0; k < K_ITEMS; ++k) {
            if (act[k]) {
                if (v[k] == key[k])     { found[k] = true; act[k] = false; }
                else if (v[k] < key[k]) { lo[k] = mid[k]; vlo[k] = v[k]; }
                else                    { hi[k] = mid[k]; vhi[k] = v[k]; }
                if (hi[k] - lo[k] <= 8) act[k] = false;
            }
        }
    }

    // binary fallback; w.h.p. never runs (exec-masked skip)
    #pragma unroll
    for (int k = 0; k < K_ITEMS; ++k) {
        while (hi[k] - lo[k] > 8) {
            int m = lo[k] + ((hi[k] - lo[k]) >> 1);
            u64 v = (u64)table[m];
            if (v == key[k]) { found[k] = true; break; }
            if (v < key[k]) lo[k] = m; else hi[k] = m;
        }
    }

    // final scan: 7 independent clamped loads per chain. Safe unconditionally:
    // table is strictly sorted-unique, entries outside (lo,hi) are != key.
    #pragma unroll
    for (int k = 0; k < K_ITEMS; ++k) {
        u64 e[7];
        #pragma unroll
        for (int j = 0; j < 7; ++j) {
            int idx = lo[k] + 1 + j;
            if (idx > L - 1) idx = L - 1;
            e[j] = (u64)table[idx];
        }
        bool eq = false;
        #pragma unroll
        for (int j = 0; j < 7; ++j) eq |= (e[j] == key[k]);
        found[k] |= eq;
    }

    #pragma unroll
    for (int k = 0; k < K_ITEMS; ++k)
        out_keep[i0 + (unsigned)k] = found[k] ? 0 : 1;
}

// ---------------- kernel / launch -------------------------------------------

__global__ __launch_bounds__(256) void neg_sample_kernel(
    const void* __restrict__ pos, const void* __restrict__ rand_vals,
    const void* __restrict__ table,
    int* __restrict__ out_neg, int* __restrict__ out_keep,
    int total, int split, int L, unsigned num_negs)
{
    unsigned t = blockIdx.x * blockDim.x + threadIdx.x;
    unsigned i0 = t * (unsigned)K_ITEMS;
    if (i0 >= (unsigned)total) return;

    // Width probe (R2-proven): pos int32-view word 3 == 0 iff int64 storage.
    const int* pw = (const int*)pos;
    const bool is64 = (pw[3] == 0);   // wave-uniform, L1-hot

    if (i0 + (unsigned)K_ITEMS <= (unsigned)total) {
        if (is64) sample_body_k<i64>((const i64*)pos, (const i64*)rand_vals,
                                     (const i64*)table, out_neg, out_keep,
                                     i0, split, L, num_negs);
        else      sample_body_k<int>((const int*)pos, (const int*)rand_vals,
                                     (const int*)table, out_neg, out_keep,
                                     i0, split, L, num_negs);
    } else {
        for (unsigned i = i0; i < (unsigned)total; ++i) {
            if (is64) sample_body<i64>((const i64*)pos, (const i64*)rand_vals,
                                       (const i64*)table, out_neg, out_keep,
                                       i, split, L, num_negs);
            else      sample_body<int>((const int*)pos, (const int*)rand_vals,
                                       (const int*)table, out_neg, out_keep,
                                       i, split, L, num_negs);
        }
    }
}

extern "C" void kernel_launch(void* const* d_in, const int* in_sizes, int n_in,
                              void* d_out, int out_size, void* d_ws, size_t ws_size,
                              hipStream_t stream) {
    const void* pos       = d_in[0];
    const void* rand_vals = d_in[1];
    const void* table     = d_in[2];

    const int B     = in_sizes[0] / 3;
    const int total = in_sizes[1];
    const int L     = in_sizes[2];
    const unsigned num_negs = (unsigned)(total / B);
    const int split = (total + 1) / 2;   // ceil(total/2)

    int* out_neg  = (int*)d_out;
    int* out_keep = out_neg + (size_t)total * 3;

    const int threads = 256;
    const int items_per_block = threads * K_ITEMS;
    const int blocks = (total + items_per_block - 1) / items_per_block;
    neg_sample_kernel<<<blocks, threads, 0, stream>>>(
        pos, rand_vals, table, out_neg, out_keep, total, split, L, num_negs);
}

// Round 2
// 96.584 us; speedup vs baseline: 1.6254x; 1.6254x over previous
//
#include <hip/hip_runtime.h>

typedef long long i64;
typedef unsigned long long u64;

// ---------------------------------------------------------------------------
// Established facts (R1-R11):
//  - int64 inputs; int32 output [total*3] neg then [total] keep.
//  - R4/R8: PASS, kernel ~53 us, VALUBusy ~45%, occ ~71%, FETCH 9.5 MB,
//    WRITE 65.5 MB (1.2 TB/s -- far from BW ceiling).
//  - R8 (broadcast tail search): NEUTRAL => NOT gather/L2-BW bound.
//  - R10 (K=4 lockstep ILP): REGRESSED 53->88 us. VALUBusy unchanged ~46%,
//    occupancy 71->46.5%, and 53*(71/46.5)=81 ~= 88. CONCLUSION: kernel is
//    latency-bound with time ~ 1/(resident waves); per-thread ILP does not
//    substitute for TLP here. Occupancy is the lever, not ILP.
//  - Harness dur_us includes a fixed ~43 us fillBufferAligned we can't touch.
//  - Proven shell: ONE dispatch, width probe, no d_ws, no atomics, no
//    cross-lane intrinsics.
// R12: revert to R4 scalar structure (K=1) +
//  (a) final window scan as 4x ulonglong2 (16B) loads from an aligned base
//      covering the whole <=8-entry window: 7 gathers -> 4, independent.
//  (b) block 256 -> 128 for finer WG packing (occupancy probe).
// ---------------------------------------------------------------------------

template <typename T>
__device__ __forceinline__ bool interp_member(const T* __restrict__ table,
                                              int L, u64 key) {
    u64 v0 = (u64)table[0];
    u64 vN = (u64)table[L - 1];
    if (key <= v0) return key == v0;
    if (key >= vN) return key == vN;
    // invariant: table[lo] < key < table[hi]
    int lo = 0, hi = L - 1;
    u64 vlo = v0, vhi = vN;
    for (int it = 0; it < 12 && hi - lo > 8; ++it) {
        // f32 is plenty: rounding error ~ window * 6e-8 < 1 entry.
        float f = (float)(key - vlo) * __builtin_amdgcn_rcpf((float)(vhi - vlo));
        int mid = lo + (int)(f * (float)(hi - lo));
        if (mid <= lo) mid = lo + 1;           // clamp => strict shrink both ways
        if (mid >= hi) mid = hi - 1;
        u64 v = (u64)table[mid];
        if (v == key) return true;
        if (v < key) { lo = mid; vlo = v; }
        else         { hi = mid; vhi = v; }
    }
    while (hi - lo > 8) {                      // fallback; w.h.p. never runs
        int mid = lo + ((hi - lo) >> 1);
        u64 v = (u64)table[mid];
        if (v == key) return true;
        if (v < key) lo = mid; else hi = mid;
    }
    // Final scan of interior (lo, hi), <=7 entries.
    // i64 path: 4x 16B loads from aligned base m0.
    //  - m0 = (lo+1)&~1 in {lo, lo+1}; m0+7 >= lo+7 >= hi-1  => window covered.
    //  - clamp m0<=L-8 only triggers when lo >= L-8, and then [L-8, L-1]
    //    still covers the interior. 16B alignment: m0 even, table 8B-typed,
    //    hipMalloc base 256B-aligned.
    //  - no false positives: table is strictly sorted-unique and
    //    table[lo] < key < table[hi], so every entry outside (lo,hi) != key.
    if constexpr (sizeof(T) == 8) {
        if (L >= 8) {
            int m0 = (lo + 1) & ~1;
            if (m0 > L - 8) m0 = L - 8;
            const ulonglong2* p = (const ulonglong2*)(table + m0);
            ulonglong2 a = p[0];
            ulonglong2 b = p[1];
            ulonglong2 c = p[2];
            ulonglong2 d = p[3];
            return (a.x == key) | (a.y == key) | (b.x == key) | (b.y == key) |
                   (c.x == key) | (c.y == key) | (d.x == key) | (d.y == key);
        }
    }
    bool eq = false;                           // int path / tiny-L: scalar scan
    for (int j = lo + 1; j < hi; ++j) eq |= ((u64)table[j] == key);
    return eq;
}

template <typename T>
__device__ __forceinline__ void sample_body(
    const T* __restrict__ pos, const T* __restrict__ rand_vals,
    const T* __restrict__ table,
    int* __restrict__ out_neg, int* __restrict__ out_keep,
    unsigned i, int split, int L, unsigned num_negs)
{
    unsigned b = i / num_negs;   // num_negs=64 -> shift
    i64 h = (i64)pos[3 * b + 0];
    i64 r = (i64)pos[3 * b + 1];
    i64 t = (i64)pos[3 * b + 2];
    i64 rv = (i64)rand_vals[i];

    const bool corrupt_head = (i < (unsigned)split);
    i64 orig = corrupt_head ? h : t;
    // pad_idx==0 fast path: rng drawn in [1, NUM_ENTITIES); shift past original
    i64 repl = rv + (((rv >= orig) & (orig > 0)) ? 1 : 0);
    if (corrupt_head) h = repl; else t = repl;

    u64 key = ((u64)h << 42) | ((u64)r << 21) | (u64)t;

    // Store neg early: fire-and-forget, frees values during the search.
    out_neg[3 * (size_t)i + 0] = (int)h;
    out_neg[3 * (size_t)i + 1] = (int)r;
    out_neg[3 * (size_t)i + 2] = (int)t;

    bool in_set = interp_member(table, L, key);
    out_keep[i] = in_set ? 0 : 1;
}

__global__ __launch_bounds__(128) void neg_sample_kernel(
    const void* __restrict__ pos, const void* __restrict__ rand_vals,
    const void* __restrict__ table,
    int* __restrict__ out_neg, int* __restrict__ out_keep,
    int total, int split, int L, unsigned num_negs)
{
    unsigned i = blockIdx.x * blockDim.x + threadIdx.x;
    if (i >= (unsigned)total) return;

    // Width probe (R2-proven): pos int32-view word 3 == 0 iff int64 storage.
    const int* pw = (const int*)pos;
    const bool is64 = (pw[3] == 0);   // wave-uniform, L1-hot

    if (is64) {
        sample_body<i64>((const i64*)pos, (const i64*)rand_vals, (const i64*)table,
                         out_neg, out_keep, i, split, L, num_negs);
    } else {
        sample_body<int>((const int*)pos, (const int*)rand_vals, (const int*)table,
                         out_neg, out_keep, i, split, L, num_negs);
    }
}

extern "C" void kernel_launch(void* const* d_in, const int* in_sizes, int n_in,
                              void* d_out, int out_size, void* d_ws, size_t ws_size,
                              hipStream_t stream) {
    const void* pos       = d_in[0];
    const void* rand_vals = d_in[1];
    const void* table     = d_in[2];

    const int B     = in_sizes[0] / 3;
    const int total = in_sizes[1];
    const int L     = in_sizes[2];
    const unsigned num_negs = (unsigned)(total / B);
    const int split = (total + 1) / 2;   // ceil(total/2)

    int* out_neg  = (int*)d_out;
    int* out_keep = out_neg + (size_t)total * 3;

    const int threads = 128;
    const int blocks  = (total + threads - 1) / threads;
    neg_sample_kernel<<<blocks, threads, 0, stream>>>(
        pos, rand_vals, table, out_neg, out_keep, total, split, L, num_negs);
}